// Round 6
// baseline (176.821 us; speedup 1.0000x reference)
//
#include <hip/hip_runtime.h>
#include <math.h>

// Problem constants (fixed by the reference)
#define NQ   1024      // B*LT
#define DIM  512
#define NH   8
#define DHD  64
#define DFF  2048
#define LM   64        // LMEM

typedef __bf16 bf16x8 __attribute__((ext_vector_type(8)));
typedef float  f32x4  __attribute__((ext_vector_type(4)));

__device__ __forceinline__ unsigned short f2bf(float f) {
    unsigned u = __builtin_bit_cast(unsigned, f);
    return (unsigned short)((u + 0x7fffu + ((u >> 16) & 1u)) >> 16);
}
__device__ __forceinline__ float bflo(unsigned p) {
    return __builtin_bit_cast(float, p << 16);
}
__device__ __forceinline__ float bfhi(unsigned p) {
    return __builtin_bit_cast(float, p & 0xffff0000u);
}

__device__ __forceinline__ void gload16(const void* g, void* l) {
    __builtin_amdgcn_global_load_lds(
        (const __attribute__((address_space(1))) unsigned*)g,
        (__attribute__((address_space(3))) unsigned*)l, 16, 0, 0);
}

// ---------------------------------------------------------------- helpers
__device__ __forceinline__ float blk_sum(float v, volatile float* red) {
#pragma unroll
    for (int o = 32; o; o >>= 1) v += __shfl_down(v, o);
    __syncthreads();
    if ((threadIdx.x & 63) == 0) red[threadIdx.x >> 6] = v;
    __syncthreads();
    return red[0] + red[1] + red[2] + red[3];
}

// ------------------------------------------------- K1: prep (fold GEMMs + FFN
//   transpose + bias folds) + LN0 + argmax, all one launch.
struct PrepArgs {
    const float *Wq, *Wk, *Wv, *Wo, *bq, *bv, *bo;
    unsigned short *wqk, *wvo;      // [8][512][512] bf16 each (Bt layout)
    float *bqk, *bvo;               // [8][512], [512]
    const float* fsrc[4];           // f1W1, f1W2, f2W1, f2W2
    unsigned short* fdst[4];        // transposed bf16
    const float *dec_out, *attn_out, *g0, *be0;
    float* x; unsigned* xb; int* samples;
};
__global__ __launch_bounds__(256) void prep_ln0_k(PrepArgs P) {
    __shared__ float ldsA[64][65];
    __shared__ float ldsB[64][65];
    __shared__ float tile[32][33];
    __shared__ float red[4];
    __shared__ float rv[4]; __shared__ int ri[4];
    const int bid = blockIdx.x, t = threadIdx.x;

    if (bid < 1024) {
        // fold GEMM: out[c][k] = sum_j A'(c,j) * B'(k,j), K=64, per head h
        // mat0 (wqk): A' = Wk rows (c0+c), cols h64+j ; B' = Wq rows (k0+k)
        // mat1 (wvo): A' = Wo rows h64+j, cols (c0+c) ; B' = Wv rows (k0+k)
        const int mat = bid >> 9, rem = bid & 511;
        const int h = rem >> 6, tl = rem & 63;
        const int c0 = (tl >> 3) * 64, k0 = (tl & 7) * 64;
        const float* Bsrc = mat ? P.Wv : P.Wq;
        for (int idx = t; idx < 1024; idx += 256) {       // 64 rows x 16 float4
            int k = idx >> 4, j4 = idx & 15;
            float4 v = *(const float4*)&Bsrc[(size_t)(k0 + k) * 512 + h * 64 + j4 * 4];
            ldsB[k][j4 * 4 + 0] = v.x; ldsB[k][j4 * 4 + 1] = v.y;
            ldsB[k][j4 * 4 + 2] = v.z; ldsB[k][j4 * 4 + 3] = v.w;
        }
        if (mat == 0) {
            for (int idx = t; idx < 1024; idx += 256) {
                int c = idx >> 4, j4 = idx & 15;
                float4 v = *(const float4*)&P.Wk[(size_t)(c0 + c) * 512 + h * 64 + j4 * 4];
                ldsA[c][j4 * 4 + 0] = v.x; ldsA[c][j4 * 4 + 1] = v.y;
                ldsA[c][j4 * 4 + 2] = v.z; ldsA[c][j4 * 4 + 3] = v.w;
            }
        } else {
            for (int idx = t; idx < 1024; idx += 256) {
                int j = idx >> 4, c4 = idx & 15;
                float4 v = *(const float4*)&P.Wo[(size_t)(h * 64 + j) * 512 + c0 + c4 * 4];
                ldsA[c4 * 4 + 0][j] = v.x; ldsA[c4 * 4 + 1][j] = v.y;
                ldsA[c4 * 4 + 2][j] = v.z; ldsA[c4 * 4 + 3][j] = v.w;
            }
        }
        __syncthreads();
        const int ty = t >> 4, tx = t & 15;
        float acc[4][4] = {};
#pragma unroll 8
        for (int j = 0; j < 64; ++j) {
            float a0 = ldsA[ty * 4 + 0][j], a1 = ldsA[ty * 4 + 1][j];
            float a2 = ldsA[ty * 4 + 2][j], a3 = ldsA[ty * 4 + 3][j];
            float b0 = ldsB[tx * 4 + 0][j], b1 = ldsB[tx * 4 + 1][j];
            float b2 = ldsB[tx * 4 + 2][j], b3 = ldsB[tx * 4 + 3][j];
            acc[0][0] = fmaf(a0, b0, acc[0][0]); acc[0][1] = fmaf(a0, b1, acc[0][1]);
            acc[0][2] = fmaf(a0, b2, acc[0][2]); acc[0][3] = fmaf(a0, b3, acc[0][3]);
            acc[1][0] = fmaf(a1, b0, acc[1][0]); acc[1][1] = fmaf(a1, b1, acc[1][1]);
            acc[1][2] = fmaf(a1, b2, acc[1][2]); acc[1][3] = fmaf(a1, b3, acc[1][3]);
            acc[2][0] = fmaf(a2, b0, acc[2][0]); acc[2][1] = fmaf(a2, b1, acc[2][1]);
            acc[2][2] = fmaf(a2, b2, acc[2][2]); acc[2][3] = fmaf(a2, b3, acc[2][3]);
            acc[3][0] = fmaf(a3, b0, acc[3][0]); acc[3][1] = fmaf(a3, b1, acc[3][1]);
            acc[3][2] = fmaf(a3, b2, acc[3][2]); acc[3][3] = fmaf(a3, b3, acc[3][3]);
        }
        unsigned short* dst = mat ? P.wvo : P.wqk;
#pragma unroll
        for (int i = 0; i < 4; ++i) {
            size_t o = ((size_t)h * 512 + c0 + ty * 4 + i) * 512 + k0 + tx * 4;
            dst[o + 0] = f2bf(acc[i][0]); dst[o + 1] = f2bf(acc[i][1]);
            dst[o + 2] = f2bf(acc[i][2]); dst[o + 3] = f2bf(acc[i][3]);
        }
        return;
    }
    if (bid < 5120) {
        // FFN weight transpose fp32 -> bf16
        const int f = (bid - 1024) >> 10, lt = (bid - 1024) & 1023;
        const int RS = (f & 1) ? 2048 : 512;   // dst leading rows count source cols
        const int CS = (f & 1) ? 512 : 2048;
        const int TC = CS >> 5;
        const int tr = lt / TC, tc = lt % TC;
        const float* s = P.fsrc[f];
        unsigned short* d = P.fdst[f];
        const int tx = t & 31, ty = t >> 5;
#pragma unroll
        for (int i = 0; i < 32; i += 8)
            tile[ty + i][tx] = s[(size_t)(tr * 32 + ty + i) * CS + tc * 32 + tx];
        __syncthreads();
#pragma unroll
        for (int i = 0; i < 32; i += 8)
            d[(size_t)(tc * 32 + ty + i) * RS + tr * 32 + tx] = f2bf(tile[tx][ty + i]);
        return;
    }
    if (bid < 5128) {       // bqk[h][d] = sum_j bq[h64+j] * Wk[d][h64+j]
        const int h = bid - 5120;
#pragma unroll
        for (int rep = 0; rep < 2; ++rep) {
            int d = t + rep * 256;
            float a = 0.f;
            for (int j = 0; j < 64; ++j)
                a += P.bq[h * 64 + j] * P.Wk[(size_t)d * 512 + h * 64 + j];
            P.bqk[h * 512 + d] = a;
        }
        return;
    }
    if (bid < 5130) {       // bvo[c] = bo[c] + sum_d bv[d]*Wo[d][c]
        const int c = (bid - 5128) * 256 + t;
        float a = P.bo[c];
        for (int d = 0; d < 512; ++d) a += P.bv[d] * P.Wo[(size_t)d * 512 + c];
        P.bvo[c] = a;
        return;
    }
    if (bid < 5136) return;

    // LN0 + argmax
    const int n = bid - 5136;
    float2 v = ((const float2*)(P.dec_out + (size_t)n * DIM))[t];
    float mu  = blk_sum(v.x + v.y, red) * (1.f / DIM);
    float dx = v.x - mu, dy = v.y - mu;
    float var = blk_sum(dx * dx + dy * dy, red) * (1.f / DIM);
    float rs = rsqrtf(var + 1e-5f);
    float2 gg = ((const float2*)P.g0)[t], bb = ((const float2*)P.be0)[t];
    float ox = dx * rs * gg.x + bb.x, oy = dy * rs * gg.y + bb.y;
    ((float2*)(P.x + (size_t)n * DIM))[t] = make_float2(ox, oy);
    P.xb[(size_t)n * 256 + t] = (unsigned)f2bf(ox) | ((unsigned)f2bf(oy) << 16);

    const float* ar = P.attn_out + (size_t)n * 1025;
    float bvx = -INFINITY; int bi = 0x7fffffff;
    for (int i = t; i < 1025; i += 256) {
        float val = ar[i];
        if (val > bvx || (val == bvx && i < bi)) { bvx = val; bi = i; }
    }
#pragma unroll
    for (int o = 32; o; o >>= 1) {
        float ov = __shfl_down(bvx, o); int oi = __shfl_down(bi, o);
        if (ov > bvx || (ov == bvx && oi < bi)) { bvx = ov; bi = oi; }
    }
    if ((t & 63) == 0) { rv[t >> 6] = bvx; ri[t >> 6] = bi; }
    __syncthreads();
    if (t == 0) {
#pragma unroll
        for (int w = 1; w < 4; ++w)
            if (rv[w] > bvx || (rv[w] == bvx && ri[w] < bi)) { bvx = rv[w]; bi = ri[w]; }
        P.samples[n] = bi - 1;
    }
}

// ------------------------------------------------- bf16 MFMA GEMM, 64x64 tile
template<bool RELU, bool BIAS, bool RES, bool WF32, bool WBF>
__global__ __launch_bounds__(256) void mfma_gemm(
    const unsigned short* __restrict__ A, const unsigned short* __restrict__ Bt,
    float* __restrict__ Cf, unsigned short* __restrict__ Cb,
    const float* __restrict__ bias, const float* __restrict__ res,
    int K, int lda, int ldb, int ldc,
    int sA, int sB, int sC, int sBias)
{
    __shared__ unsigned short Ab[2][64 * 64];
    __shared__ unsigned short Bb[2][64 * 64];
    const int t = threadIdx.x, lane = t & 63, wid = t >> 6;
    const int bm = blockIdx.y * 64, bn = blockIdx.x * 64, bz = blockIdx.z;
    const unsigned short* Abase = A + (size_t)bz * sA + (size_t)bm * lda;
    const unsigned short* Bbase = Bt + (size_t)bz * sB + (size_t)bn * ldb;

    const int r0 = wid * 16 + (lane >> 3);
    const int cbs = lane & 7;

#define STAGE_T(buf, base, ld, kt)                                              \
    {                                                                           \
        int r_ = r0;                                                            \
        gload16(base + (size_t)r_ * ld + (kt) * 64 + ((cbs ^ (r_ & 7)) << 3),   \
                &buf[(wid * 2 + 0) * 512]);                                     \
        r_ = r0 + 8;                                                            \
        gload16(base + (size_t)r_ * ld + (kt) * 64 + ((cbs ^ (r_ & 7)) << 3),   \
                &buf[(wid * 2 + 1) * 512]);                                     \
    }

    const int lr = lane & 15, lg = lane >> 4;
    const int wr = (wid >> 1) * 32, wc = (wid & 1) * 32;
    const int mA0 = wr + lr, mA1 = wr + 16 + lr;
    const int nB0 = wc + lr, nB1 = wc + 16 + lr;
    f32x4 acc[2][2] = {};

#define COMPUTE(b)                                                              \
    _Pragma("unroll")                                                           \
    for (int kk = 0; kk < 2; ++kk) {                                            \
        const int kb = kk * 4 + lg;                                             \
        bf16x8 a0 = *(const bf16x8*)&Ab[b][mA0 * 64 + ((kb ^ (mA0 & 7)) << 3)]; \
        bf16x8 a1 = *(const bf16x8*)&Ab[b][mA1 * 64 + ((kb ^ (mA1 & 7)) << 3)]; \
        bf16x8 b0 = *(const bf16x8*)&Bb[b][nB0 * 64 + ((kb ^ (nB0 & 7)) << 3)]; \
        bf16x8 b1 = *(const bf16x8*)&Bb[b][nB1 * 64 + ((kb ^ (nB1 & 7)) << 3)]; \
        acc[0][0] = __builtin_amdgcn_mfma_f32_16x16x32_bf16(a0, b0, acc[0][0], 0, 0, 0); \
        acc[0][1] = __builtin_amdgcn_mfma_f32_16x16x32_bf16(a0, b1, acc[0][1], 0, 0, 0); \
        acc[1][0] = __builtin_amdgcn_mfma_f32_16x16x32_bf16(a1, b0, acc[1][0], 0, 0, 0); \
        acc[1][1] = __builtin_amdgcn_mfma_f32_16x16x32_bf16(a1, b1, acc[1][1], 0, 0, 0); \
    }

    STAGE_T(Ab[0], Abase, lda, 0);
    STAGE_T(Bb[0], Bbase, ldb, 0);
    __syncthreads();
    const int NT = K >> 6;
    int cur = 0;
    for (int kt = 0; kt < NT; ++kt) {
        if (kt + 1 < NT) {
            STAGE_T(Ab[cur ^ 1], Abase, lda, kt + 1);
            STAGE_T(Bb[cur ^ 1], Bbase, ldb, kt + 1);
        }
        if (cur == 0) { COMPUTE(0); } else { COMPUTE(1); }
        __syncthreads();
        cur ^= 1;
    }

#pragma unroll
    for (int fm = 0; fm < 2; ++fm)
#pragma unroll
    for (int fn = 0; fn < 2; ++fn) {
        const int col = bn + wc + fn * 16 + lr;
        float bia = BIAS ? bias[bz * sBias + col] : 0.f;
#pragma unroll
        for (int r = 0; r < 4; ++r) {
            const int row = bm + wr + fm * 16 + lg * 4 + r;
            const size_t ci = (size_t)bz * sC + (size_t)row * ldc + col;
            float v = acc[fm][fn][r] + bia;
            if (RES) v += res[(size_t)row * ldc + col];
            if (RELU) v = fmaxf(v, 0.f);
            if (WF32) Cf[ci] = v;
            if (WBF)  Cb[ci] = f2bf(v);
        }
    }
#undef STAGE_T
#undef COMPUTE
}

// ------------------------------------------------- K3: partial scores via MFMA
// block (n, half): S_part[n][half][h][k] = enc[s,k, half*256..+256]·u[n,h,same]
// (the k-invariant qh·bk term is dropped: softmax is shift-invariant over k)
__global__ __launch_bounds__(256) void attn_scores_k(
    const unsigned short* __restrict__ u_bf, const float* __restrict__ enc,
    const int* __restrict__ samples, float* __restrict__ s_part)
{
    const int n = blockIdx.x, half = blockIdx.y, t = threadIdx.x;
    const int lane = t & 63, w = t >> 6;
    int s = samples[n]; if (s < 0) s = 0;

    const float4* kb = (const float4*)(enc + (size_t)s * (LM * DIM));
    const int key = w * 16 + (lane & 15);
    const int lg = lane >> 4;
    const int h = lane & 15;
    const int base = key * 128 + half * 64 + lg * 2;   // float4 units
    float4 pf[4][2];
#pragma unroll
    for (int ss = 0; ss < 4; ++ss) {
        pf[ss][0] = kb[base + ss * 8];
        pf[ss][1] = kb[base + ss * 8 + 1];
    }

    const unsigned short* ub = u_bf + (size_t)n * 4096 + (size_t)(h & 7) * 512 + half * 256;
    f32x4 acc = {};
#pragma unroll
    for (int step = 0; step < 8; ++step) {
        float4 a0 = pf[step & 3][0], a1 = pf[step & 3][1];
        if (step + 4 < 8) {
            pf[step & 3][0] = kb[base + (step + 4) * 8];
            pf[step & 3][1] = kb[base + (step + 4) * 8 + 1];
        }
        bf16x8 af;
        af[0] = (__bf16)a0.x; af[1] = (__bf16)a0.y;
        af[2] = (__bf16)a0.z; af[3] = (__bf16)a0.w;
        af[4] = (__bf16)a1.x; af[5] = (__bf16)a1.y;
        af[6] = (__bf16)a1.z; af[7] = (__bf16)a1.w;
        bf16x8 bfr = *(const bf16x8*)&ub[(step * 4 + lg) * 8];
        acc = __builtin_amdgcn_mfma_f32_16x16x32_bf16(af, bfr, acc, 0, 0, 0);
    }
    if (h < 8) {
        float* sp = s_part + (((size_t)n * 2 + half) * 8 + h) * 64 + w * 16 + lg * 4;
        *(float4*)sp = make_float4(acc[0], acc[1], acc[2], acc[3]);
    }
}

// ------------------------------------------------- K4: softmax + PV (d-halved)
__global__ __launch_bounds__(256) void attn_pv_k(
    const float* __restrict__ s_part, const float* __restrict__ vemb,
    const int* __restrict__ maskmem, const int* __restrict__ samples,
    unsigned* __restrict__ a_bf)
{
    __shared__ float Sp_lds[1024];
    __shared__ uint4 P_lds[64];
    __shared__ float2 Red[8][128];
    __shared__ int Msk_lds[64];
    const int n = blockIdx.x, dh = blockIdx.y, t = threadIdx.x;
    const int lane = t & 63, w = t >> 6;
    int s = samples[n]; if (s < 0) s = 0;

    ((float4*)Sp_lds)[t] = ((const float4*)(s_part + (size_t)n * 1024))[t];
    if (t < 64) Msk_lds[t] = maskmem[(size_t)s * LM + t];
    __syncthreads();

#pragma unroll
    for (int hh = 0; hh < 2; ++hh) {
        const int h = w + hh * 4;
        float sc = (Sp_lds[h * 64 + lane] + Sp_lds[512 + h * 64 + lane]) * 0.125f;
        sc = (Msk_lds[lane] != 0) ? sc : -1e9f;
        float m = sc;
#pragma unroll
        for (int o = 32; o; o >>= 1) m = fmaxf(m, __shfl_xor(m, o));
        float e = __expf(sc - m);
        float su = e;
#pragma unroll
        for (int o = 32; o; o >>= 1) su += __shfl_xor(su, o);
        ((unsigned short*)P_lds)[lane * 8 + h] = f2bf(e / su);
    }
    __syncthreads();

    const int c = t & 127, kh = t >> 7;
    const float2* vb = (const float2*)(vemb + (size_t)s * (LM * DIM)) + dh * 128 + c;
    float2 acc8[8];
#pragma unroll
    for (int hh = 0; hh < 8; ++hh) acc8[hh] = make_float2(0.f, 0.f);
#pragma unroll 8
    for (int i = 0; i < 32; ++i) {
        const int k = kh * 32 + i;
        float2 v = vb[(size_t)k * 256];
        uint4 pr = P_lds[k];
        float p0 = bflo(pr.x), p1 = bfhi(pr.x);
        float p2 = bflo(pr.y), p3 = bfhi(pr.y);
        float p4 = bflo(pr.z), p5 = bfhi(pr.z);
        float p6 = bflo(pr.w), p7 = bfhi(pr.w);
        acc8[0].x = fmaf(p0, v.x, acc8[0].x); acc8[0].y = fmaf(p0, v.y, acc8[0].y);
        acc8[1].x = fmaf(p1, v.x, acc8[1].x); acc8[1].y = fmaf(p1, v.y, acc8[1].y);
        acc8[2].x = fmaf(p2, v.x, acc8[2].x); acc8[2].y = fmaf(p2, v.y, acc8[2].y);
        acc8[3].x = fmaf(p3, v.x, acc8[3].x); acc8[3].y = fmaf(p3, v.y, acc8[3].y);
        acc8[4].x = fmaf(p4, v.x, acc8[4].x); acc8[4].y = fmaf(p4, v.y, acc8[4].y);
        acc8[5].x = fmaf(p5, v.x, acc8[5].x); acc8[5].y = fmaf(p5, v.y, acc8[5].y);
        acc8[6].x = fmaf(p6, v.x, acc8[6].x); acc8[6].y = fmaf(p6, v.y, acc8[6].y);
        acc8[7].x = fmaf(p7, v.x, acc8[7].x); acc8[7].y = fmaf(p7, v.y, acc8[7].y);
    }
    if (kh == 1) {
#pragma unroll
        for (int hh = 0; hh < 8; ++hh) Red[hh][c] = acc8[hh];
    }
    __syncthreads();
    if (kh == 0) {
        unsigned* an = a_bf + (size_t)n * 2048 + dh * 128;
#pragma unroll
        for (int hh = 0; hh < 8; ++hh) {
            float2 r = Red[hh][c];
            float ox = acc8[hh].x + r.x, oy = acc8[hh].y + r.y;
            an[hh * 256 + c] = (unsigned)f2bf(ox) | ((unsigned)f2bf(oy) << 16);
        }
    }
}

// ------------------------------------------------- K6: merge ST0 partials
// st0 = x + sum_z stov[z] + bvo   (f32 + bf16 outputs)
__global__ __launch_bounds__(256) void merge_st0_k(
    const float* __restrict__ stov, const float* __restrict__ x,
    const float* __restrict__ bvo,
    float* __restrict__ st0f, unsigned* __restrict__ st0b)
{
    const int n = blockIdx.x, t = threadIdx.x;
    const size_t off = (size_t)n * DIM + t * 2;
    float2 acc = *(const float2*)&x[off];
    float2 bv2 = ((const float2*)bvo)[t];
    acc.x += bv2.x; acc.y += bv2.y;
#pragma unroll
    for (int z = 0; z < 8; ++z) {
        float2 p = *(const float2*)&stov[(size_t)z * (NQ * DIM) + off];
        acc.x += p.x; acc.y += p.y;
    }
    *(float2*)&st0f[off] = acc;
    st0b[(size_t)n * 256 + t] = (unsigned)f2bf(acc.x) | ((unsigned)f2bf(acc.y) << 16);
}

// ------------------------------------------------- K8: combine T1 parts + LN + mask + x
__global__ __launch_bounds__(256) void ln1_mask_add_k(
    const float* __restrict__ t1p, const float* __restrict__ st0,
    const float* __restrict__ b2, const float* __restrict__ g,
    const float* __restrict__ be, const int* __restrict__ samples,
    const float* __restrict__ x, float* __restrict__ dec, unsigned* __restrict__ decb)
{
    __shared__ float red[4];
    const int n = blockIdx.x, t = threadIdx.x;
    const size_t off = (size_t)n * DIM + t * 2;
    float2 s0 = *(const float2*)&st0[off];
    float2 b2v = ((const float2*)b2)[t];
    float2 v = make_float2(s0.x + b2v.x, s0.y + b2v.y);
#pragma unroll
    for (int z = 0; z < 4; ++z) {
        float2 p = *(const float2*)&t1p[(size_t)z * (NQ * DIM) + off];
        v.x += p.x; v.y += p.y;
    }
    float mu  = blk_sum(v.x + v.y, red) * (1.f / DIM);
    float dx = v.x - mu, dy = v.y - mu;
    float var = blk_sum(dx * dx + dy * dy, red) * (1.f / DIM);
    float rs = rsqrtf(var + 1e-5f);
    float2 gg = ((const float2*)g)[t], bb = ((const float2*)be)[t];
    float sx = dx * rs * gg.x + bb.x, sy = dy * rs * gg.y + bb.y;
    if (samples[n] < 0) { sx = 0.f; sy = 0.f; }
    float2 xx = *(const float2*)&x[off];
    float ox = xx.x + sx, oy = xx.y + sy;
    *(float2*)&dec[off] = make_float2(ox, oy);
    decb[(size_t)n * 256 + t] = (unsigned)f2bf(ox) | ((unsigned)f2bf(oy) << 16);
}

// ---------------------------------------------------------------- launcher
extern "C" void kernel_launch(void* const* d_in, const int* in_sizes, int n_in,
                              void* d_out, int out_size, void* d_ws, size_t ws_size,
                              hipStream_t stream)
{
    const float* dec_output = (const float*)d_in[0];
    const float* mem_attn   = (const float*)d_in[1];
    const float* enc_mem    = (const float*)d_in[2];
    const float* temb_mem   = (const float*)d_in[3];
    const int*   mask_mem   = (const int*)d_in[4];
    const float* g0  = (const float*)d_in[6];
    const float* be0 = (const float*)d_in[7];
    const float* g1  = (const float*)d_in[8];
    const float* be1 = (const float*)d_in[9];
    const float* Wq  = (const float*)d_in[10];
    const float* bq  = (const float*)d_in[11];
    const float* Wk  = (const float*)d_in[12];
    const float* Wv  = (const float*)d_in[14];
    const float* bv  = (const float*)d_in[15];
    const float* Wo  = (const float*)d_in[16];
    const float* bo  = (const float*)d_in[17];
    const float* f1W1 = (const float*)d_in[18];
    const float* f1b1 = (const float*)d_in[19];
    const float* f1W2 = (const float*)d_in[20];
    const float* f1b2 = (const float*)d_in[21];
    const float* f2W1 = (const float*)d_in[22];
    const float* f2b1 = (const float*)d_in[23];
    const float* f2W2 = (const float*)d_in[24];
    const float* f2b2 = (const float*)d_in[25];
    float* out = (float*)d_out;

    float* ws = (float*)d_ws;
    // persistent (offsets in floats)
    float*          x_f   = ws + 0;                          // 524288
    unsigned*       x_b   = (unsigned*)(ws + 524288);        // 262144
    unsigned short* u_b   = (unsigned short*)(ws + 786432);  // 2097152
    unsigned short* a_b   = (unsigned short*)(ws + 2883584); // 2097152
    float*          s_prt = ws + 4980736;                    // 1048576
    unsigned short* wqk   = (unsigned short*)(ws + 6029312); // 1048576
    unsigned short* wvo   = (unsigned short*)(ws + 7077888); // 1048576
    unsigned short* f1w1t = (unsigned short*)(ws + 8126464); // 524288 each
    unsigned short* f1w2t = (unsigned short*)(ws + 8650752);
    unsigned short* f2w1t = (unsigned short*)(ws + 9175040);
    unsigned short* f2w2t = (unsigned short*)(ws + 9699328);
    float*          bqk   = ws + 10223616;                   // 4096
    float*          bvo   = ws + 10227712;                   // 512
    int*            smp   = (int*)(ws + 10228224);           // 1024
    float*          stov  = ws + 10229248;                   // 4194304 (8 x 1024x512 f32)
    float*          t1p_f = ws + 14423552;                   // 2097152 (4 parts)
    // aliases inside u_b region (u dead after attn_scores):
    float*          st0_f = (float*)u_b + 0;                 // 524288
    unsigned short* st0_b = (unsigned short*)((float*)u_b + 524288); // 131072
    float*          dec_f = (float*)u_b + 655360;            // 524288
    unsigned*       dec_b = (unsigned*)((float*)u_b + 1179648); // 131072
    // aliases inside a_b region (a dead after avo GEMM):
    unsigned short* h1_b  = a_b;                             // 1024x2048 bf16
    unsigned short* h2_b  = (unsigned short*)((float*)a_b + 1048576);

    PrepArgs P;
    P.Wq = Wq; P.Wk = Wk; P.Wv = Wv; P.Wo = Wo; P.bq = bq; P.bv = bv; P.bo = bo;
    P.wqk = wqk; P.wvo = wvo; P.bqk = bqk; P.bvo = bvo;
    P.fsrc[0] = f1W1; P.fdst[0] = f1w1t;
    P.fsrc[1] = f1W2; P.fdst[1] = f1w2t;
    P.fsrc[2] = f2W1; P.fdst[2] = f2w1t;
    P.fsrc[3] = f2W2; P.fdst[3] = f2w2t;
    P.dec_out = dec_output; P.attn_out = mem_attn; P.g0 = g0; P.be0 = be0;
    P.x = x_f; P.xb = x_b; P.samples = smp;

    // 1. prep (weight folds + transposes + biases) + LN0 + argmax
    prep_ln0_k<<<6160, 256, 0, stream>>>(P);
    // 2. U_h = X @ Wqk_h + bqk_h  (batched heads, K=512, 1024 blocks)
    mfma_gemm<false, true, false, false, true><<<dim3(8, 16, NH), 256, 0, stream>>>(
        (const unsigned short*)x_b, wqk, nullptr, u_b, bqk, nullptr,
        DIM, DIM, DIM, NH * DIM, /*sA*/0, /*sB*/DIM * DIM, /*sC*/DIM, /*sBias*/DIM);
    // 3. partial scores (split over 2 D-halves)
    attn_scores_k<<<dim3(NQ, 2), 256, 0, stream>>>(u_b, enc_mem, smp, s_prt);
    // 4. softmax + PV -> a (bf16)
    attn_pv_k<<<dim3(NQ, 2), 256, 0, stream>>>(s_prt, temb_mem, mask_mem, smp,
                                               (unsigned*)a_b);
    // 5. ST0 partials: stov[h] = A_h @ Wvo_h  (head-split-K, 1024 blocks)
    mfma_gemm<false, false, false, true, false><<<dim3(8, 16, NH), 256, 0, stream>>>(
        a_b, wvo, stov, nullptr, nullptr, nullptr,
        DIM, NH * DIM, DIM, DIM, /*sA*/DIM, /*sB*/DIM * DIM, /*sC*/NQ * DIM, 0);
    // 6. ST0 = X + sum_h stov[h] + bvo
    merge_st0_k<<<NQ, 256, 0, stream>>>(stov, x_f, bvo, st0_f, (unsigned*)st0_b);
    // 7. H1 = relu(ST0 @ f1W1 + f1b1)
    mfma_gemm<true, true, false, false, true><<<dim3(32, 16, 1), 256, 0, stream>>>(
        st0_b, f1w1t, nullptr, h1_b, f1b1, nullptr, DIM, DIM, DIM, DFF, 0, 0, 0, 0);
    // 8. T1 parts = H1 @ f1W2 (split-K=4; bias/res merged in LN1)
    mfma_gemm<false, false, false, true, false><<<dim3(8, 16, 4), 256, 0, stream>>>(
        h1_b, f1w2t, t1p_f, nullptr, nullptr, nullptr,
        DIM, DFF, DFF, DIM, /*sA*/DIM, /*sB*/DIM, /*sC*/NQ * DIM, 0);
    // 9. DEC = X + mask * LN1(sum parts + ST0 + f1b2)
    ln1_mask_add_k<<<NQ, 256, 0, stream>>>(t1p_f, st0_f, f1b2, g1, be1, smp,
                                           x_f, dec_f, dec_b);
    // 10. H2 = relu(DEC @ f2W1 + f2b1)
    mfma_gemm<true, true, false, false, true><<<dim3(32, 16, 1), 256, 0, stream>>>(
        (const unsigned short*)dec_b, f2w1t, nullptr, h2_b, f2b1, nullptr,
        DIM, DIM, DIM, DFF, 0, 0, 0, 0);
    // 11. OUT = DEC + H2 @ f2W2 + f2b2
    mfma_gemm<false, true, true, true, false><<<dim3(8, 16, 1), 256, 0, stream>>>(
        h2_b, f2w2t, out, nullptr, f2b2, dec_f, DFF, DFF, DFF, DIM, 0, 0, 0, 0);

    (void)in_sizes; (void)n_in; (void)out_size; (void)ws_size;
}

// Round 7
// 156.740 us; speedup vs baseline: 1.1281x; 1.1281x over previous
//
#include <hip/hip_runtime.h>
#include <math.h>

// Problem constants (fixed by the reference)
#define NQ   1024      // B*LT
#define DIM  512
#define NH   8
#define DHD  64
#define DFF  2048
#define LM   64        // LMEM

typedef __bf16 bf16x8 __attribute__((ext_vector_type(8)));
typedef float  f32x4  __attribute__((ext_vector_type(4)));

__device__ __forceinline__ unsigned short f2bf(float f) {
    unsigned u = __builtin_bit_cast(unsigned, f);
    return (unsigned short)((u + 0x7fffu + ((u >> 16) & 1u)) >> 16);
}
__device__ __forceinline__ float bflo(unsigned p) {
    return __builtin_bit_cast(float, p << 16);
}
__device__ __forceinline__ float bfhi(unsigned p) {
    return __builtin_bit_cast(float, p & 0xffff0000u);
}

__device__ __forceinline__ void gload16(const void* g, void* l) {
    __builtin_amdgcn_global_load_lds(
        (const __attribute__((address_space(1))) unsigned*)g,
        (__attribute__((address_space(3))) unsigned*)l, 16, 0, 0);
}

// ---------------------------------------------------------------- helpers
__device__ __forceinline__ float blk_sum(float v, volatile float* red) {
#pragma unroll
    for (int o = 32; o; o >>= 1) v += __shfl_down(v, o);
    __syncthreads();
    if ((threadIdx.x & 63) == 0) red[threadIdx.x >> 6] = v;
    __syncthreads();
    return red[0] + red[1] + red[2] + red[3];
}

// ------------------------------------------------- K1: weight-prep + LN0 + argmax
struct PrepPtrs {
    const float* src[8];
    unsigned short* dst[8];
};
// blocks [0,5120): weight prep; blocks [5120,6144): LN0+argmax for n = bid-5120
__global__ __launch_bounds__(256) void prep_ln0_k(
    PrepPtrs p,
    const float* __restrict__ dec_out, const float* __restrict__ attn_out,
    const float* __restrict__ g, const float* __restrict__ be,
    float* __restrict__ x, unsigned* __restrict__ xb, int* __restrict__ samples)
{
    __shared__ float tile[32][33];
    __shared__ float red[4];
    __shared__ float rv[4]; __shared__ int ri[4];
    const int bid = blockIdx.x;

    if (bid < 5120) {
        int m, lt;
        if (bid < 1024) { m = bid >> 8; lt = bid & 255; }
        else { m = 4 + ((bid - 1024) >> 10); lt = (bid - 1024) & 1023; }
        const int RS = (m < 4) ? 512 : ((m == 5 || m == 7) ? 2048 : 512);
        const int CS = (m < 4) ? 512 : ((m == 5 || m == 7) ? 512 : 2048);
        const int TC = CS >> 5;
        const int tr = lt / TC, tc = lt % TC;
        const float* s = p.src[m];
        unsigned short* d = p.dst[m];
        const int tx = threadIdx.x & 31, ty = threadIdx.x >> 5;
        if (m == 1) {
#pragma unroll
            for (int i = 0; i < 32; i += 8) {
                size_t idx = (size_t)(tr * 32 + ty + i) * CS + tc * 32 + tx;
                d[idx] = f2bf(s[idx]);
            }
        } else {
#pragma unroll
            for (int i = 0; i < 32; i += 8)
                tile[ty + i][tx] = s[(size_t)(tr * 32 + ty + i) * CS + tc * 32 + tx];
            __syncthreads();
#pragma unroll
            for (int i = 0; i < 32; i += 8)
                d[(size_t)(tc * 32 + ty + i) * RS + tr * 32 + tx] = f2bf(tile[tx][ty + i]);
        }
        return;
    }

    const int n = bid - 5120, t = threadIdx.x;
    float2 v = ((const float2*)(dec_out + (size_t)n * DIM))[t];
    float mu  = blk_sum(v.x + v.y, red) * (1.f / DIM);
    float dx = v.x - mu, dy = v.y - mu;
    float var = blk_sum(dx * dx + dy * dy, red) * (1.f / DIM);
    float rs = rsqrtf(var + 1e-5f);
    float2 gg = ((const float2*)g)[t], bb = ((const float2*)be)[t];
    float ox = dx * rs * gg.x + bb.x, oy = dy * rs * gg.y + bb.y;
    ((float2*)(x + (size_t)n * DIM))[t] = make_float2(ox, oy);
    xb[(size_t)n * 256 + t] = (unsigned)f2bf(ox) | ((unsigned)f2bf(oy) << 16);

    const float* ar = attn_out + (size_t)n * 1025;
    float bv = -INFINITY; int bi = 0x7fffffff;
    for (int i = t; i < 1025; i += 256) {
        float val = ar[i];
        if (val > bv || (val == bv && i < bi)) { bv = val; bi = i; }
    }
#pragma unroll
    for (int o = 32; o; o >>= 1) {
        float ov = __shfl_down(bv, o); int oi = __shfl_down(bi, o);
        if (ov > bv || (ov == bv && oi < bi)) { bv = ov; bi = oi; }
    }
    if ((t & 63) == 0) { rv[t >> 6] = bv; ri[t >> 6] = bi; }
    __syncthreads();
    if (t == 0) {
#pragma unroll
        for (int w = 1; w < 4; ++w)
            if (rv[w] > bv || (rv[w] == bv && ri[w] < bi)) { bv = rv[w]; bi = ri[w]; }
        samples[n] = bi - 1;
    }
}

// ------------------------------------------------- bf16 MFMA GEMM, 64x64 tile
// XCD-aware tile swizzle: requires gridDim.x*gridDim.y % 8 == 0.
template<bool RELU, bool BIAS, bool RES, bool WF32, bool WBF>
__global__ __launch_bounds__(256) void mfma_gemm(
    const unsigned short* __restrict__ A, const unsigned short* __restrict__ Bt,
    float* __restrict__ Cf, unsigned short* __restrict__ Cb,
    const float* __restrict__ bias, const float* __restrict__ res,
    int K, int lda, int ldb, int ldc,
    int sA, int sB, int sC, int sBias)
{
    __shared__ unsigned short Ab[2][64 * 64];
    __shared__ unsigned short Bb[2][64 * 64];
    const int t = threadIdx.x, lane = t & 63, wid = t >> 6;
    const int nx = gridDim.x;
    const int fid = blockIdx.y * nx + blockIdx.x;
    const int cpx = (nx * gridDim.y) >> 3;
    const int f2 = (fid & 7) * cpx + (fid >> 3);
    const int bn = (f2 % nx) * 64, bm = (f2 / nx) * 64, bz = blockIdx.z;
    const unsigned short* Abase = A + (size_t)bz * sA + (size_t)bm * lda;
    const unsigned short* Bbase = Bt + (size_t)bz * sB + (size_t)bn * ldb;

    const int r0 = wid * 16 + (lane >> 3);
    const int cbs = lane & 7;

#define STAGE_T(buf, base, ld, kt)                                              \
    {                                                                           \
        int r_ = r0;                                                            \
        gload16(base + (size_t)r_ * ld + (kt) * 64 + ((cbs ^ (r_ & 7)) << 3),   \
                &buf[(wid * 2 + 0) * 512]);                                     \
        r_ = r0 + 8;                                                            \
        gload16(base + (size_t)r_ * ld + (kt) * 64 + ((cbs ^ (r_ & 7)) << 3),   \
                &buf[(wid * 2 + 1) * 512]);                                     \
    }

    const int lr = lane & 15, lg = lane >> 4;
    const int wr = (wid >> 1) * 32, wc = (wid & 1) * 32;
    const int mA0 = wr + lr, mA1 = wr + 16 + lr;
    const int nB0 = wc + lr, nB1 = wc + 16 + lr;
    f32x4 acc[2][2] = {};

#define COMPUTE(b)                                                              \
    _Pragma("unroll")                                                           \
    for (int kk = 0; kk < 2; ++kk) {                                            \
        const int kb = kk * 4 + lg;                                             \
        bf16x8 a0 = *(const bf16x8*)&Ab[b][mA0 * 64 + ((kb ^ (mA0 & 7)) << 3)]; \
        bf16x8 a1 = *(const bf16x8*)&Ab[b][mA1 * 64 + ((kb ^ (mA1 & 7)) << 3)]; \
        bf16x8 b0 = *(const bf16x8*)&Bb[b][nB0 * 64 + ((kb ^ (nB0 & 7)) << 3)]; \
        bf16x8 b1 = *(const bf16x8*)&Bb[b][nB1 * 64 + ((kb ^ (nB1 & 7)) << 3)]; \
        acc[0][0] = __builtin_amdgcn_mfma_f32_16x16x32_bf16(a0, b0, acc[0][0], 0, 0, 0); \
        acc[0][1] = __builtin_amdgcn_mfma_f32_16x16x32_bf16(a0, b1, acc[0][1], 0, 0, 0); \
        acc[1][0] = __builtin_amdgcn_mfma_f32_16x16x32_bf16(a1, b0, acc[1][0], 0, 0, 0); \
        acc[1][1] = __builtin_amdgcn_mfma_f32_16x16x32_bf16(a1, b1, acc[1][1], 0, 0, 0); \
    }

    STAGE_T(Ab[0], Abase, lda, 0);
    STAGE_T(Bb[0], Bbase, ldb, 0);
    __syncthreads();
    const int NT = K >> 6;
    int cur = 0;
    for (int kt = 0; kt < NT; ++kt) {
        if (kt + 1 < NT) {
            STAGE_T(Ab[cur ^ 1], Abase, lda, kt + 1);
            STAGE_T(Bb[cur ^ 1], Bbase, ldb, kt + 1);
        }
        if (cur == 0) { COMPUTE(0); } else { COMPUTE(1); }
        __syncthreads();
        cur ^= 1;
    }

#pragma unroll
    for (int fm = 0; fm < 2; ++fm)
#pragma unroll
    for (int fn = 0; fn < 2; ++fn) {
        const int col = bn + wc + fn * 16 + lr;
        float bia = BIAS ? bias[bz * sBias + col] : 0.f;
#pragma unroll
        for (int r = 0; r < 4; ++r) {
            const int row = bm + wr + fm * 16 + lg * 4 + r;
            const size_t ci = (size_t)bz * sC + (size_t)row * ldc + col;
            float v = acc[fm][fn][r] + bia;
            if (RES) v += res[(size_t)row * ldc + col];
            if (RELU) v = fmaxf(v, 0.f);
            if (WF32) Cf[ci] = v;
            if (WBF)  Cb[ci] = f2bf(v);
        }
    }
#undef STAGE_T
#undef COMPUTE
}

// ------------------------------------------------- K4: partial scores via MFMA
// block (n, q): S_part[n][q][h][k] = enc[s,k, q*128..+128]·u[n,h,q*128..+128]
// (the k-invariant qh·bk term is dropped: softmax is shift-invariant over k)
__global__ __launch_bounds__(256) void attn_scores_k(
    const unsigned short* __restrict__ u_bf, const float* __restrict__ enc,
    const int* __restrict__ samples, float* __restrict__ s_part)
{
    const int n = blockIdx.x, q = blockIdx.y, t = threadIdx.x;
    const int lane = t & 63, w = t >> 6;
    int s = samples[n]; if (s < 0) s = 0;

    const float4* kb = (const float4*)(enc + (size_t)s * (LM * DIM));
    const int key = w * 16 + (lane & 15);
    const int lg = lane >> 4;
    const int h = lane & 15;
    const int base = key * 128 + q * 32 + lg * 2;   // float4 units
    float4 pf[4][2];
#pragma unroll
    for (int ss = 0; ss < 4; ++ss) {
        pf[ss][0] = kb[base + ss * 8];
        pf[ss][1] = kb[base + ss * 8 + 1];
    }

    const unsigned short* ub = u_bf + (size_t)n * 4096 + (size_t)(h & 7) * 512 + q * 128;
    f32x4 acc = {};
#pragma unroll
    for (int step = 0; step < 4; ++step) {
        float4 a0 = pf[step][0], a1 = pf[step][1];
        bf16x8 af;
        af[0] = (__bf16)a0.x; af[1] = (__bf16)a0.y;
        af[2] = (__bf16)a0.z; af[3] = (__bf16)a0.w;
        af[4] = (__bf16)a1.x; af[5] = (__bf16)a1.y;
        af[6] = (__bf16)a1.z; af[7] = (__bf16)a1.w;
        bf16x8 bfr = *(const bf16x8*)&ub[(step * 4 + lg) * 8];
        acc = __builtin_amdgcn_mfma_f32_16x16x32_bf16(af, bfr, acc, 0, 0, 0);
    }
    if (h < 8) {
        float* sp = s_part + (((size_t)n * 4 + q) * 8 + h) * 64 + w * 16 + lg * 4;
        *(float4*)sp = make_float4(acc[0], acc[1], acc[2], acc[3]);
    }
}

// ------------------------------------------------- K5: softmax + PV (d-quartered)
__global__ __launch_bounds__(256) void attn_pv_k(
    const float* __restrict__ s_part, const float* __restrict__ vemb,
    const int* __restrict__ maskmem, const int* __restrict__ samples,
    unsigned* __restrict__ a_bf)
{
    __shared__ float Sp_lds[2048];
    __shared__ uint4 P_lds[64];
    __shared__ float2 Red[3][8][64];
    __shared__ int Msk_lds[64];
    const int n = blockIdx.x, dq = blockIdx.y, t = threadIdx.x;
    const int lane = t & 63, w = t >> 6;
    int s = samples[n]; if (s < 0) s = 0;

    ((float4*)Sp_lds)[t]       = ((const float4*)(s_part + (size_t)n * 2048))[t];
    ((float4*)Sp_lds)[t + 256] = ((const float4*)(s_part + (size_t)n * 2048))[t + 256];
    if (t < 64) Msk_lds[t] = maskmem[(size_t)s * LM + t];
    __syncthreads();

    // softmax: wave w handles heads w and w+4 (key = lane)
#pragma unroll
    for (int hh = 0; hh < 2; ++hh) {
        const int h = w + hh * 4;
        float sc = (Sp_lds[h * 64 + lane] + Sp_lds[512 + h * 64 + lane]
                  + Sp_lds[1024 + h * 64 + lane] + Sp_lds[1536 + h * 64 + lane]) * 0.125f;
        sc = (Msk_lds[lane] != 0) ? sc : -1e9f;
        float m = sc;
#pragma unroll
        for (int o = 32; o; o >>= 1) m = fmaxf(m, __shfl_xor(m, o));
        float e = __expf(sc - m);
        float su = e;
#pragma unroll
        for (int o = 32; o; o >>= 1) su += __shfl_xor(su, o);
        ((unsigned short*)P_lds)[lane * 8 + h] = f2bf(e / su);
    }
    __syncthreads();

    // PV: quarter dq of output dims (128 floats = 64 float2); 4 k-groups of 16
    const int c = t & 63, kh = t >> 6;
    const float2* vb = (const float2*)(vemb + (size_t)s * (LM * DIM)) + dq * 64 + c;
    float2 acc8[8];
#pragma unroll
    for (int hh = 0; hh < 8; ++hh) acc8[hh] = make_float2(0.f, 0.f);
#pragma unroll 8
    for (int i = 0; i < 16; ++i) {
        const int k = kh * 16 + i;
        float2 v = vb[(size_t)k * 256];
        uint4 pr = P_lds[k];
        float p0 = bflo(pr.x), p1 = bfhi(pr.x);
        float p2 = bflo(pr.y), p3 = bfhi(pr.y);
        float p4 = bflo(pr.z), p5 = bfhi(pr.z);
        float p6 = bflo(pr.w), p7 = bfhi(pr.w);
        acc8[0].x = fmaf(p0, v.x, acc8[0].x); acc8[0].y = fmaf(p0, v.y, acc8[0].y);
        acc8[1].x = fmaf(p1, v.x, acc8[1].x); acc8[1].y = fmaf(p1, v.y, acc8[1].y);
        acc8[2].x = fmaf(p2, v.x, acc8[2].x); acc8[2].y = fmaf(p2, v.y, acc8[2].y);
        acc8[3].x = fmaf(p3, v.x, acc8[3].x); acc8[3].y = fmaf(p3, v.y, acc8[3].y);
        acc8[4].x = fmaf(p4, v.x, acc8[4].x); acc8[4].y = fmaf(p4, v.y, acc8[4].y);
        acc8[5].x = fmaf(p5, v.x, acc8[5].x); acc8[5].y = fmaf(p5, v.y, acc8[5].y);
        acc8[6].x = fmaf(p6, v.x, acc8[6].x); acc8[6].y = fmaf(p6, v.y, acc8[6].y);
        acc8[7].x = fmaf(p7, v.x, acc8[7].x); acc8[7].y = fmaf(p7, v.y, acc8[7].y);
    }
    if (kh > 0) {
#pragma unroll
        for (int hh = 0; hh < 8; ++hh) Red[kh - 1][hh][c] = acc8[hh];
    }
    __syncthreads();
    if (kh == 0) {
        unsigned* an = a_bf + (size_t)n * 2048 + dq * 64;
#pragma unroll
        for (int hh = 0; hh < 8; ++hh) {
            float2 r0 = Red[0][hh][c], r1 = Red[1][hh][c], r2 = Red[2][hh][c];
            float ox = acc8[hh].x + r0.x + r1.x + r2.x;
            float oy = acc8[hh].y + r0.y + r1.y + r2.y;
            an[hh * 256 + c] = (unsigned)f2bf(ox) | ((unsigned)f2bf(oy) << 16);
        }
    }
}

// ------------------------------------------------- K10: combine T1 parts + LN + mask + x
__global__ __launch_bounds__(256) void ln1_mask_add_k(
    const float* __restrict__ t1p, const float* __restrict__ st0,
    const float* __restrict__ b2, const float* __restrict__ g,
    const float* __restrict__ be, const int* __restrict__ samples,
    const float* __restrict__ x, float* __restrict__ dec, unsigned* __restrict__ decb)
{
    __shared__ float red[4];
    const int n = blockIdx.x, t = threadIdx.x;
    const size_t off = (size_t)n * DIM + t * 2;
    float2 p0 = *(const float2*)&t1p[off];
    float2 p1 = *(const float2*)&t1p[(size_t)NQ * DIM + off];
    float2 s0 = *(const float2*)&st0[off];
    float2 b2v = ((const float2*)b2)[t];
    float2 v = make_float2(p0.x + p1.x + s0.x + b2v.x, p0.y + p1.y + s0.y + b2v.y);
    float mu  = blk_sum(v.x + v.y, red) * (1.f / DIM);
    float dx = v.x - mu, dy = v.y - mu;
    float var = blk_sum(dx * dx + dy * dy, red) * (1.f / DIM);
    float rs = rsqrtf(var + 1e-5f);
    float2 gg = ((const float2*)g)[t], bb = ((const float2*)be)[t];
    float sx = dx * rs * gg.x + bb.x, sy = dy * rs * gg.y + bb.y;
    if (samples[n] < 0) { sx = 0.f; sy = 0.f; }
    float2 xx = *(const float2*)&x[off];
    float ox = xx.x + sx, oy = xx.y + sy;
    *(float2*)&dec[off] = make_float2(ox, oy);
    decb[(size_t)n * 256 + t] = (unsigned)f2bf(ox) | ((unsigned)f2bf(oy) << 16);
}

// ---------------------------------------------------------------- launcher
extern "C" void kernel_launch(void* const* d_in, const int* in_sizes, int n_in,
                              void* d_out, int out_size, void* d_ws, size_t ws_size,
                              hipStream_t stream)
{
    const float* dec_output = (const float*)d_in[0];
    const float* mem_attn   = (const float*)d_in[1];
    const float* enc_mem    = (const float*)d_in[2];
    const float* temb_mem   = (const float*)d_in[3];
    const int*   mask_mem   = (const int*)d_in[4];
    const float* g0  = (const float*)d_in[6];
    const float* be0 = (const float*)d_in[7];
    const float* g1  = (const float*)d_in[8];
    const float* be1 = (const float*)d_in[9];
    const float* Wq  = (const float*)d_in[10];
    const float* bq  = (const float*)d_in[11];
    const float* Wk  = (const float*)d_in[12];
    const float* Wv  = (const float*)d_in[14];
    const float* bv  = (const float*)d_in[15];
    const float* Wo  = (const float*)d_in[16];
    const float* bo  = (const float*)d_in[17];
    const float* f1W1 = (const float*)d_in[18];
    const float* f1b1 = (const float*)d_in[19];
    const float* f1W2 = (const float*)d_in[20];
    const float* f1b2 = (const float*)d_in[21];
    const float* f2W1 = (const float*)d_in[22];
    const float* f2b1 = (const float*)d_in[23];
    const float* f2W2 = (const float*)d_in[24];
    const float* f2b2 = (const float*)d_in[25];
    float* out = (float*)d_out;

    float* ws = (float*)d_ws;
    // persistent (offsets in floats)
    float*          x_f   = ws + 0;                          // 524288
    unsigned*       x_b   = (unsigned*)(ws + 524288);        // 262144
    unsigned short* qh_b  = (unsigned short*)(ws + 786432);  // 262144
    unsigned short* u_b   = (unsigned short*)(ws + 1048576); // 2097152
    unsigned short* a_b   = (unsigned short*)(ws + 3145728); // 2097152
    float*          s_prt = ws + 5242880;                    // 2097152 (8 MB)
    unsigned short* wqt   = (unsigned short*)(ws + 7340032); // 131072 each
    unsigned short* wkc   = (unsigned short*)(ws + 7471104);
    unsigned short* wvt   = (unsigned short*)(ws + 7602176);
    unsigned short* wot   = (unsigned short*)(ws + 7733248);
    unsigned short* f1w1t = (unsigned short*)(ws + 7864320); // 524288 each
    unsigned short* f1w2t = (unsigned short*)(ws + 8388608);
    unsigned short* f2w1t = (unsigned short*)(ws + 8912896);
    unsigned short* f2w2t = (unsigned short*)(ws + 9437184);
    int*            smp   = (int*)(ws + 9961472);            // 1024
    float*          t1p_f = ws + 9962496;                    // 1048576 (2 parts)
    // aliases inside u_b region (u dead after attn_scores):
    float*          st0_f = (float*)u_b + 0;                 // 524288
    unsigned short* st0_b = (unsigned short*)((float*)u_b + 524288); // 131072
    float*          dec_f = (float*)u_b + 655360;            // 524288
    unsigned*       dec_b = (unsigned*)((float*)u_b + 1179648); // 131072
    // aliases inside a_b region (a dead after CTX GEMM):
    unsigned short* h1_b  = a_b;                             // 1024x2048 bf16
    unsigned short* h2_b  = (unsigned short*)((float*)a_b + 1048576);

    PrepPtrs pp;
    pp.src[0] = Wq;   pp.dst[0] = wqt;
    pp.src[1] = Wk;   pp.dst[1] = wkc;
    pp.src[2] = Wv;   pp.dst[2] = wvt;
    pp.src[3] = Wo;   pp.dst[3] = wot;
    pp.src[4] = f1W1; pp.dst[4] = f1w1t;
    pp.src[5] = f1W2; pp.dst[5] = f1w2t;
    pp.src[6] = f2W1; pp.dst[6] = f2w1t;
    pp.src[7] = f2W2; pp.dst[7] = f2w2t;
    // 1. weight prep + LN0 + argmax
    prep_ln0_k<<<5120 + NQ, 256, 0, stream>>>(pp, dec_output, mem_attn, g0, be0,
                                              x_f, x_b, smp);
    // 2. QH = X @ Wq + bq  (bf16 out only)
    mfma_gemm<false, true, false, false, true><<<dim3(8, 16, 1), 256, 0, stream>>>(
        (const unsigned short*)x_b, wqt, nullptr, qh_b, bq, nullptr,
        DIM, DIM, DIM, DIM, 0, 0, 0, 0);
    // 3. U_h = QH_h @ Wk_h^T (batched heads, K=64)
    mfma_gemm<false, false, false, false, true><<<dim3(8, 16, NH), 256, 0, stream>>>(
        qh_b, wkc, nullptr, u_b, nullptr, nullptr,
        DHD, DIM, DIM, NH * DIM, DHD, DHD, DIM, 0);
    // 4. partial scores (split over 4 dim-quarters)
    attn_scores_k<<<dim3(NQ, 4), 256, 0, stream>>>(u_b, enc_mem, smp, s_prt);
    // 5. softmax + PV -> a (bf16), 4 output-quarters
    attn_pv_k<<<dim3(NQ, 4), 256, 0, stream>>>(s_prt, temb_mem, mask_mem, smp,
                                               (unsigned*)a_b);
    // 6. CTX_h = A_h @ Wv_h + bv_h
    mfma_gemm<false, true, false, false, true><<<dim3(1, 16, NH), 256, 0, stream>>>(
        a_b, wvt, nullptr, qh_b, bv, nullptr,
        DIM, NH * DIM, DIM, DIM, DIM, DHD * DIM, DHD, DHD);
    // 7. ST0 = X + CTX @ Wo + bo
    mfma_gemm<false, true, true, true, true><<<dim3(8, 16, 1), 256, 0, stream>>>(
        qh_b, wot, st0_f, st0_b, bo, x_f, DIM, DIM, DIM, DIM, 0, 0, 0, 0);
    // 8. H1 = relu(ST0 @ f1W1 + f1b1)
    mfma_gemm<true, true, false, false, true><<<dim3(32, 16, 1), 256, 0, stream>>>(
        st0_b, f1w1t, nullptr, h1_b, f1b1, nullptr, DIM, DIM, DIM, DFF, 0, 0, 0, 0);
    // 9. T1 parts = H1 @ f1W2 (split-K=2; bias/res merged in LN1)
    mfma_gemm<false, false, false, true, false><<<dim3(8, 16, 2), 256, 0, stream>>>(
        h1_b, f1w2t, t1p_f, nullptr, nullptr, nullptr,
        1024, DFF, DFF, DIM, 1024, 1024, NQ * DIM, 0);
    // 10. DEC = X + mask * LN1(p0 + p1 + ST0 + f1b2)
    ln1_mask_add_k<<<NQ, 256, 0, stream>>>(t1p_f, st0_f, f1b2, g1, be1, smp,
                                           x_f, dec_f, dec_b);
    // 11. H2 = relu(DEC @ f2W1 + f2b1)
    mfma_gemm<true, true, false, false, true><<<dim3(32, 16, 1), 256, 0, stream>>>(
        (const unsigned short*)dec_b, f2w1t, nullptr, h2_b, f2b1, nullptr,
        DIM, DIM, DIM, DFF, 0, 0, 0, 0);
    // 12. OUT = DEC + H2 @ f2W2 + f2b2
    mfma_gemm<false, true, true, true, false><<<dim3(8, 16, 1), 256, 0, stream>>>(
        h2_b, f2w2t, out, nullptr, f2b2, dec_f, DFF, DFF, DFF, DIM, 0, 0, 0, 0);

    (void)in_sizes; (void)n_in; (void)out_size; (void)ws_size;
}

// Round 8
// 153.218 us; speedup vs baseline: 1.1540x; 1.0230x over previous
//
#include <hip/hip_runtime.h>
#include <math.h>

// Problem constants (fixed by the reference)
#define NQ   1024      // B*LT
#define DIM  512
#define NH   8
#define DHD  64
#define DFF  2048
#define LM   64        // LMEM

typedef __bf16 bf16x8 __attribute__((ext_vector_type(8)));
typedef float  f32x4  __attribute__((ext_vector_type(4)));

__device__ __forceinline__ unsigned short f2bf(float f) {
    unsigned u = __builtin_bit_cast(unsigned, f);
    return (unsigned short)((u + 0x7fffu + ((u >> 16) & 1u)) >> 16);
}
__device__ __forceinline__ float bflo(unsigned p) {
    return __builtin_bit_cast(float, p << 16);
}
__device__ __forceinline__ float bfhi(unsigned p) {
    return __builtin_bit_cast(float, p & 0xffff0000u);
}

__device__ __forceinline__ void gload16(const void* g, void* l) {
    __builtin_amdgcn_global_load_lds(
        (const __attribute__((address_space(1))) unsigned*)g,
        (__attribute__((address_space(3))) unsigned*)l, 16, 0, 0);
}

// ---------------------------------------------------------------- helpers
__device__ __forceinline__ float blk_sum(float v, volatile float* red) {
#pragma unroll
    for (int o = 32; o; o >>= 1) v += __shfl_down(v, o);
    __syncthreads();
    if ((threadIdx.x & 63) == 0) red[threadIdx.x >> 6] = v;
    __syncthreads();
    return red[0] + red[1] + red[2] + red[3];
}

// ------------------------------------------------- K1: weight-prep + LN0 + argmax
struct PrepPtrs {
    const float* src[8];
    unsigned short* dst[8];
};
// blocks [0,5120): weight prep; blocks [5120,6144): LN0+argmax for n = bid-5120
__global__ __launch_bounds__(256) void prep_ln0_k(
    PrepPtrs p,
    const float* __restrict__ dec_out, const float* __restrict__ attn_out,
    const float* __restrict__ g, const float* __restrict__ be,
    float* __restrict__ x, unsigned* __restrict__ xb, int* __restrict__ samples)
{
    __shared__ float tile[32][33];
    __shared__ float red[4];
    __shared__ float rv[4]; __shared__ int ri[4];
    const int bid = blockIdx.x;

    if (bid < 5120) {
        int m, lt;
        if (bid < 1024) { m = bid >> 8; lt = bid & 255; }
        else { m = 4 + ((bid - 1024) >> 10); lt = (bid - 1024) & 1023; }
        const int RS = (m < 4) ? 512 : ((m == 5 || m == 7) ? 2048 : 512);
        const int CS = (m < 4) ? 512 : ((m == 5 || m == 7) ? 512 : 2048);
        const int TC = CS >> 5;
        const int tr = lt / TC, tc = lt % TC;
        const float* s = p.src[m];
        unsigned short* d = p.dst[m];
        const int tx = threadIdx.x & 31, ty = threadIdx.x >> 5;
        if (m == 1) {
#pragma unroll
            for (int i = 0; i < 32; i += 8) {
                size_t idx = (size_t)(tr * 32 + ty + i) * CS + tc * 32 + tx;
                d[idx] = f2bf(s[idx]);
            }
        } else {
#pragma unroll
            for (int i = 0; i < 32; i += 8)
                tile[ty + i][tx] = s[(size_t)(tr * 32 + ty + i) * CS + tc * 32 + tx];
            __syncthreads();
#pragma unroll
            for (int i = 0; i < 32; i += 8)
                d[(size_t)(tc * 32 + ty + i) * RS + tr * 32 + tx] = f2bf(tile[tx][ty + i]);
        }
        return;
    }

    const int n = bid - 5120, t = threadIdx.x;
    float2 v = ((const float2*)(dec_out + (size_t)n * DIM))[t];
    float mu  = blk_sum(v.x + v.y, red) * (1.f / DIM);
    float dx = v.x - mu, dy = v.y - mu;
    float var = blk_sum(dx * dx + dy * dy, red) * (1.f / DIM);
    float rs = rsqrtf(var + 1e-5f);
    float2 gg = ((const float2*)g)[t], bb = ((const float2*)be)[t];
    float ox = dx * rs * gg.x + bb.x, oy = dy * rs * gg.y + bb.y;
    ((float2*)(x + (size_t)n * DIM))[t] = make_float2(ox, oy);
    xb[(size_t)n * 256 + t] = (unsigned)f2bf(ox) | ((unsigned)f2bf(oy) << 16);

    const float* ar = attn_out + (size_t)n * 1025;
    float bv = -INFINITY; int bi = 0x7fffffff;
    for (int i = t; i < 1025; i += 256) {
        float val = ar[i];
        if (val > bv || (val == bv && i < bi)) { bv = val; bi = i; }
    }
#pragma unroll
    for (int o = 32; o; o >>= 1) {
        float ov = __shfl_down(bv, o); int oi = __shfl_down(bi, o);
        if (ov > bv || (ov == bv && oi < bi)) { bv = ov; bi = oi; }
    }
    if ((t & 63) == 0) { rv[t >> 6] = bv; ri[t >> 6] = bi; }
    __syncthreads();
    if (t == 0) {
#pragma unroll
        for (int w = 1; w < 4; ++w)
            if (rv[w] > bv || (rv[w] == bv && ri[w] < bi)) { bv = rv[w]; bi = ri[w]; }
        samples[n] = bi - 1;
    }
}

// ------------------------------------------------- bf16 MFMA GEMM, 64x64 tile
// XCD-aware tile swizzle: requires gridDim.x*gridDim.y % 8 == 0.
template<bool RELU, bool BIAS, bool RES, bool WF32, bool WBF>
__global__ __launch_bounds__(256) void mfma_gemm(
    const unsigned short* __restrict__ A, const unsigned short* __restrict__ Bt,
    float* __restrict__ Cf, unsigned short* __restrict__ Cb,
    const float* __restrict__ bias, const float* __restrict__ res,
    int K, int lda, int ldb, int ldc,
    int sA, int sB, int sC, int sBias)
{
    __shared__ unsigned short Ab[2][64 * 64];
    __shared__ unsigned short Bb[2][64 * 64];
    const int t = threadIdx.x, lane = t & 63, wid = t >> 6;
    const int nx = gridDim.x;
    const int fid = blockIdx.y * nx + blockIdx.x;
    const int cpx = (nx * gridDim.y) >> 3;
    const int f2 = (fid & 7) * cpx + (fid >> 3);
    const int bn = (f2 % nx) * 64, bm = (f2 / nx) * 64, bz = blockIdx.z;
    const unsigned short* Abase = A + (size_t)bz * sA + (size_t)bm * lda;
    const unsigned short* Bbase = Bt + (size_t)bz * sB + (size_t)bn * ldb;

    const int r0 = wid * 16 + (lane >> 3);
    const int cbs = lane & 7;

#define STAGE_T(buf, base, ld, kt)                                              \
    {                                                                           \
        int r_ = r0;                                                            \
        gload16(base + (size_t)r_ * ld + (kt) * 64 + ((cbs ^ (r_ & 7)) << 3),   \
                &buf[(wid * 2 + 0) * 512]);                                     \
        r_ = r0 + 8;                                                            \
        gload16(base + (size_t)r_ * ld + (kt) * 64 + ((cbs ^ (r_ & 7)) << 3),   \
                &buf[(wid * 2 + 1) * 512]);                                     \
    }

    const int lr = lane & 15, lg = lane >> 4;
    const int wr = (wid >> 1) * 32, wc = (wid & 1) * 32;
    const int mA0 = wr + lr, mA1 = wr + 16 + lr;
    const int nB0 = wc + lr, nB1 = wc + 16 + lr;
    f32x4 acc[2][2] = {};

#define COMPUTE(b)                                                              \
    _Pragma("unroll")                                                           \
    for (int kk = 0; kk < 2; ++kk) {                                            \
        const int kb = kk * 4 + lg;                                             \
        bf16x8 a0 = *(const bf16x8*)&Ab[b][mA0 * 64 + ((kb ^ (mA0 & 7)) << 3)]; \
        bf16x8 a1 = *(const bf16x8*)&Ab[b][mA1 * 64 + ((kb ^ (mA1 & 7)) << 3)]; \
        bf16x8 b0 = *(const bf16x8*)&Bb[b][nB0 * 64 + ((kb ^ (nB0 & 7)) << 3)]; \
        bf16x8 b1 = *(const bf16x8*)&Bb[b][nB1 * 64 + ((kb ^ (nB1 & 7)) << 3)]; \
        acc[0][0] = __builtin_amdgcn_mfma_f32_16x16x32_bf16(a0, b0, acc[0][0], 0, 0, 0); \
        acc[0][1] = __builtin_amdgcn_mfma_f32_16x16x32_bf16(a0, b1, acc[0][1], 0, 0, 0); \
        acc[1][0] = __builtin_amdgcn_mfma_f32_16x16x32_bf16(a1, b0, acc[1][0], 0, 0, 0); \
        acc[1][1] = __builtin_amdgcn_mfma_f32_16x16x32_bf16(a1, b1, acc[1][1], 0, 0, 0); \
    }

    STAGE_T(Ab[0], Abase, lda, 0);
    STAGE_T(Bb[0], Bbase, ldb, 0);
    __syncthreads();
    const int NT = K >> 6;
    int cur = 0;
    for (int kt = 0; kt < NT; ++kt) {
        if (kt + 1 < NT) {
            STAGE_T(Ab[cur ^ 1], Abase, lda, kt + 1);
            STAGE_T(Bb[cur ^ 1], Bbase, ldb, kt + 1);
        }
        if (cur == 0) { COMPUTE(0); } else { COMPUTE(1); }
        __syncthreads();
        cur ^= 1;
    }

#pragma unroll
    for (int fm = 0; fm < 2; ++fm)
#pragma unroll
    for (int fn = 0; fn < 2; ++fn) {
        const int col = bn + wc + fn * 16 + lr;
        float bia = BIAS ? bias[bz * sBias + col] : 0.f;
#pragma unroll
        for (int r = 0; r < 4; ++r) {
            const int row = bm + wr + fm * 16 + lg * 4 + r;
            const size_t ci = (size_t)bz * sC + (size_t)row * ldc + col;
            float v = acc[fm][fn][r] + bia;
            if (RES) v += res[(size_t)row * ldc + col];
            if (RELU) v = fmaxf(v, 0.f);
            if (WF32) Cf[ci] = v;
            if (WBF)  Cb[ci] = f2bf(v);
        }
    }
#undef STAGE_T
#undef COMPUTE
}

// ------------------------------------------------- K4: key-split scores + partial softmax
// block (n, kq): final scores for keys [kq*32, kq*32+32) (full K=512 in-block),
// mask, then per-half softmax stats: P~=exp(s-m) bf16, (m, sumexp) per head.
__global__ __launch_bounds__(256) void attn_scores_k(
    const unsigned short* __restrict__ u_bf, const float* __restrict__ enc,
    const int* __restrict__ maskmem, const int* __restrict__ samples,
    unsigned short* __restrict__ p_half, float* __restrict__ msc)
{
    __shared__ float S_lds[2][32][8];   // [dim-half][key][head]
    const int n = blockIdx.x, kq = blockIdx.y, t = threadIdx.x;
    const int lane = t & 63, w = t >> 6;
    int s = samples[n]; if (s < 0) s = 0;

    // MFMA: wave w -> keys (w&1)*16..+16, dim-half (w>>1)
    const int keyloc = (w & 1) * 16 + (lane & 15);
    const int key = kq * 32 + keyloc;
    const int dh = w >> 1;
    const int lg = lane >> 4;
    const int h = lane & 15;
    const float4* kb = (const float4*)(enc + (size_t)s * (LM * DIM));
    const int base = key * 128 + dh * 64 + lg * 2;   // float4 units
    float4 pf[4][2];
#pragma unroll
    for (int ss = 0; ss < 4; ++ss) {
        pf[ss][0] = kb[base + ss * 8];
        pf[ss][1] = kb[base + ss * 8 + 1];
    }
    const unsigned short* ub = u_bf + (size_t)n * 4096 + (size_t)(h & 7) * 512 + dh * 256;
    f32x4 acc = {};
#pragma unroll
    for (int step = 0; step < 8; ++step) {
        float4 a0 = pf[step & 3][0], a1 = pf[step & 3][1];
        if (step + 4 < 8) {
            pf[step & 3][0] = kb[base + (step + 4) * 8];
            pf[step & 3][1] = kb[base + (step + 4) * 8 + 1];
        }
        bf16x8 af;
        af[0] = (__bf16)a0.x; af[1] = (__bf16)a0.y;
        af[2] = (__bf16)a0.z; af[3] = (__bf16)a0.w;
        af[4] = (__bf16)a1.x; af[5] = (__bf16)a1.y;
        af[6] = (__bf16)a1.z; af[7] = (__bf16)a1.w;
        bf16x8 bfr = *(const bf16x8*)&ub[(step * 4 + lg) * 8];
        acc = __builtin_amdgcn_mfma_f32_16x16x32_bf16(af, bfr, acc, 0, 0, 0);
    }
    if (h < 8) {
#pragma unroll
        for (int r = 0; r < 4; ++r)
            S_lds[dh][(w & 1) * 16 + lg * 4 + r][h] = acc[r];
    }
    __syncthreads();

    // partial softmax: thread t -> head t>>5, key t&31 (32-lane groups)
    const int h2 = t >> 5, k2 = t & 31;
    float sc = (S_lds[0][k2][h2] + S_lds[1][k2][h2]) * 0.125f;
    const int mk = maskmem[(size_t)s * LM + kq * 32 + k2];
    sc = (mk != 0) ? sc : -1e9f;
    float m = sc;
#pragma unroll
    for (int o = 16; o; o >>= 1) m = fmaxf(m, __shfl_xor(m, o));
    float e = __expf(sc - m);
    float su = e;
#pragma unroll
    for (int o = 16; o; o >>= 1) su += __shfl_xor(su, o);
    p_half[((size_t)n * 2 + kq) * 256 + k2 * 8 + h2] = f2bf(e);
    if (k2 == 0)
        ((float2*)(msc + ((size_t)n * 2 + kq) * 16))[h2] = make_float2(m, su);
}

// ------------------------------------------------- K5: online-merge softmax + PV
__global__ __launch_bounds__(256) void attn_pv_k(
    const unsigned short* __restrict__ p_half, const float* __restrict__ msc,
    const float* __restrict__ vemb, const int* __restrict__ samples,
    unsigned* __restrict__ a_bf)
{
    __shared__ uint4 P_lds[64];       // [k][8 heads] bf16
    __shared__ float2 Red[3][8][64];
    __shared__ float Wh[2][8];
    const int dq = blockIdx.x, n = blockIdx.y, t = threadIdx.x;
    int s = samples[n]; if (s < 0) s = 0;

    if (t < 8) {
        float2 ms0 = ((const float2*)(msc + (size_t)n * 32))[t];
        float2 ms1 = ((const float2*)(msc + (size_t)n * 32 + 16))[t];
        float m = fmaxf(ms0.x, ms1.x);
        float w0 = __expf(ms0.x - m), w1 = __expf(ms1.x - m);
        float inv = 1.f / (ms0.y * w0 + ms1.y * w1);
        Wh[0][t] = w0 * inv; Wh[1][t] = w1 * inv;
    }
    __syncthreads();
    {   // build normalized P tile: thread t -> key t>>2, head-pair t&3
        const int k = t >> 2, hp = t & 3, kq = k >> 5;
        unsigned v = ((const unsigned*)p_half)[((size_t)n * 2 + kq) * 128 + (k & 31) * 4 + hp];
        float a = bflo(v) * Wh[kq][hp * 2];
        float b = bfhi(v) * Wh[kq][hp * 2 + 1];
        ((unsigned*)P_lds)[k * 4 + hp] = (unsigned)f2bf(a) | ((unsigned)f2bf(b) << 16);
    }
    __syncthreads();

    // PV: quarter dq of output dims; 4 k-groups of 16
    const int c = t & 63, kh = t >> 6;
    const float2* vb = (const float2*)(vemb + (size_t)s * (LM * DIM)) + dq * 64 + c;
    float2 acc8[8];
#pragma unroll
    for (int hh = 0; hh < 8; ++hh) acc8[hh] = make_float2(0.f, 0.f);
#pragma unroll 8
    for (int i = 0; i < 16; ++i) {
        const int k = kh * 16 + i;
        float2 v = vb[(size_t)k * 256];
        uint4 pr = P_lds[k];
        float p0 = bflo(pr.x), p1 = bfhi(pr.x);
        float p2 = bflo(pr.y), p3 = bfhi(pr.y);
        float p4 = bflo(pr.z), p5 = bfhi(pr.z);
        float p6 = bflo(pr.w), p7 = bfhi(pr.w);
        acc8[0].x = fmaf(p0, v.x, acc8[0].x); acc8[0].y = fmaf(p0, v.y, acc8[0].y);
        acc8[1].x = fmaf(p1, v.x, acc8[1].x); acc8[1].y = fmaf(p1, v.y, acc8[1].y);
        acc8[2].x = fmaf(p2, v.x, acc8[2].x); acc8[2].y = fmaf(p2, v.y, acc8[2].y);
        acc8[3].x = fmaf(p3, v.x, acc8[3].x); acc8[3].y = fmaf(p3, v.y, acc8[3].y);
        acc8[4].x = fmaf(p4, v.x, acc8[4].x); acc8[4].y = fmaf(p4, v.y, acc8[4].y);
        acc8[5].x = fmaf(p5, v.x, acc8[5].x); acc8[5].y = fmaf(p5, v.y, acc8[5].y);
        acc8[6].x = fmaf(p6, v.x, acc8[6].x); acc8[6].y = fmaf(p6, v.y, acc8[6].y);
        acc8[7].x = fmaf(p7, v.x, acc8[7].x); acc8[7].y = fmaf(p7, v.y, acc8[7].y);
    }
    if (kh > 0) {
#pragma unroll
        for (int hh = 0; hh < 8; ++hh) Red[kh - 1][hh][c] = acc8[hh];
    }
    __syncthreads();
    if (kh == 0) {
        unsigned* an = a_bf + (size_t)n * 2048 + dq * 64;
#pragma unroll
        for (int hh = 0; hh < 8; ++hh) {
            float2 r0 = Red[0][hh][c], r1 = Red[1][hh][c], r2 = Red[2][hh][c];
            float ox = acc8[hh].x + r0.x + r1.x + r2.x;
            float oy = acc8[hh].y + r0.y + r1.y + r2.y;
            an[hh * 256 + c] = (unsigned)f2bf(ox) | ((unsigned)f2bf(oy) << 16);
        }
    }
}

// ------------------------------------------------- K10: combine T1 parts + LN + mask + x
__global__ __launch_bounds__(256) void ln1_mask_add_k(
    const float* __restrict__ t1p, const float* __restrict__ st0,
    const float* __restrict__ b2, const float* __restrict__ g,
    const float* __restrict__ be, const int* __restrict__ samples,
    const float* __restrict__ x, float* __restrict__ dec, unsigned* __restrict__ decb)
{
    __shared__ float red[4];
    const int n = blockIdx.x, t = threadIdx.x;
    const size_t off = (size_t)n * DIM + t * 2;
    float2 p0 = *(const float2*)&t1p[off];
    float2 p1 = *(const float2*)&t1p[(size_t)NQ * DIM + off];
    float2 s0 = *(const float2*)&st0[off];
    float2 b2v = ((const float2*)b2)[t];
    float2 v = make_float2(p0.x + p1.x + s0.x + b2v.x, p0.y + p1.y + s0.y + b2v.y);
    float mu  = blk_sum(v.x + v.y, red) * (1.f / DIM);
    float dx = v.x - mu, dy = v.y - mu;
    float var = blk_sum(dx * dx + dy * dy, red) * (1.f / DIM);
    float rs = rsqrtf(var + 1e-5f);
    float2 gg = ((const float2*)g)[t], bb = ((const float2*)be)[t];
    float sx = dx * rs * gg.x + bb.x, sy = dy * rs * gg.y + bb.y;
    if (samples[n] < 0) { sx = 0.f; sy = 0.f; }
    float2 xx = *(const float2*)&x[off];
    float ox = xx.x + sx, oy = xx.y + sy;
    *(float2*)&dec[off] = make_float2(ox, oy);
    decb[(size_t)n * 256 + t] = (unsigned)f2bf(ox) | ((unsigned)f2bf(oy) << 16);
}

// ---------------------------------------------------------------- launcher
extern "C" void kernel_launch(void* const* d_in, const int* in_sizes, int n_in,
                              void* d_out, int out_size, void* d_ws, size_t ws_size,
                              hipStream_t stream)
{
    const float* dec_output = (const float*)d_in[0];
    const float* mem_attn   = (const float*)d_in[1];
    const float* enc_mem    = (const float*)d_in[2];
    const float* temb_mem   = (const float*)d_in[3];
    const int*   mask_mem   = (const int*)d_in[4];
    const float* g0  = (const float*)d_in[6];
    const float* be0 = (const float*)d_in[7];
    const float* g1  = (const float*)d_in[8];
    const float* be1 = (const float*)d_in[9];
    const float* Wq  = (const float*)d_in[10];
    const float* bq  = (const float*)d_in[11];
    const float* Wk  = (const float*)d_in[12];
    const float* Wv  = (const float*)d_in[14];
    const float* bv  = (const float*)d_in[15];
    const float* Wo  = (const float*)d_in[16];
    const float* bo  = (const float*)d_in[17];
    const float* f1W1 = (const float*)d_in[18];
    const float* f1b1 = (const float*)d_in[19];
    const float* f1W2 = (const float*)d_in[20];
    const float* f1b2 = (const float*)d_in[21];
    const float* f2W1 = (const float*)d_in[22];
    const float* f2b1 = (const float*)d_in[23];
    const float* f2W2 = (const float*)d_in[24];
    const float* f2b2 = (const float*)d_in[25];
    float* out = (float*)d_out;

    float* ws = (float*)d_ws;
    // persistent (offsets in floats)
    float*          x_f   = ws + 0;                          // 524288
    unsigned*       x_b   = (unsigned*)(ws + 524288);        // 262144
    unsigned short* qh_b  = (unsigned short*)(ws + 786432);  // 262144
    unsigned short* u_b   = (unsigned short*)(ws + 1048576); // 2097152
    unsigned short* a_b   = (unsigned short*)(ws + 3145728); // 2097152
    unsigned short* p_hlf = (unsigned short*)(ws + 5242880); // 262144 f (1 MB bf16)
    float*          msc   = ws + 5505024;                    // 32768 f
    unsigned short* wqt   = (unsigned short*)(ws + 7340032); // 131072 each
    unsigned short* wkc   = (unsigned short*)(ws + 7471104);
    unsigned short* wvt   = (unsigned short*)(ws + 7602176);
    unsigned short* wot   = (unsigned short*)(ws + 7733248);
    unsigned short* f1w1t = (unsigned short*)(ws + 7864320); // 524288 each
    unsigned short* f1w2t = (unsigned short*)(ws + 8388608);
    unsigned short* f2w1t = (unsigned short*)(ws + 8912896);
    unsigned short* f2w2t = (unsigned short*)(ws + 9437184);
    int*            smp   = (int*)(ws + 9961472);            // 1024
    float*          t1p_f = ws + 9962496;                    // 1048576 (2 parts)
    // aliases inside u_b region (u dead after attn_scores):
    float*          st0_f = (float*)u_b + 0;                 // 524288
    unsigned short* st0_b = (unsigned short*)((float*)u_b + 524288); // 131072
    float*          dec_f = (float*)u_b + 655360;            // 524288
    unsigned*       dec_b = (unsigned*)((float*)u_b + 1179648); // 131072
    // aliases inside a_b region (a dead after CTX GEMM):
    unsigned short* h1_b  = a_b;                             // 1024x2048 bf16
    unsigned short* h2_b  = (unsigned short*)((float*)a_b + 1048576);

    PrepPtrs pp;
    pp.src[0] = Wq;   pp.dst[0] = wqt;
    pp.src[1] = Wk;   pp.dst[1] = wkc;
    pp.src[2] = Wv;   pp.dst[2] = wvt;
    pp.src[3] = Wo;   pp.dst[3] = wot;
    pp.src[4] = f1W1; pp.dst[4] = f1w1t;
    pp.src[5] = f1W2; pp.dst[5] = f1w2t;
    pp.src[6] = f2W1; pp.dst[6] = f2w1t;
    pp.src[7] = f2W2; pp.dst[7] = f2w2t;
    // 1. weight prep + LN0 + argmax
    prep_ln0_k<<<5120 + NQ, 256, 0, stream>>>(pp, dec_output, mem_attn, g0, be0,
                                              x_f, x_b, smp);
    // 2. QH = X @ Wq + bq  (bf16 out only)
    mfma_gemm<false, true, false, false, true><<<dim3(8, 16, 1), 256, 0, stream>>>(
        (const unsigned short*)x_b, wqt, nullptr, qh_b, bq, nullptr,
        DIM, DIM, DIM, DIM, 0, 0, 0, 0);
    // 3. U_h = QH_h @ Wk_h^T (batched heads, K=64)
    mfma_gemm<false, false, false, false, true><<<dim3(8, 16, NH), 256, 0, stream>>>(
        qh_b, wkc, nullptr, u_b, nullptr, nullptr,
        DHD, DIM, DIM, NH * DIM, DHD, DHD, DIM, 0);
    // 4. key-split scores + partial softmax
    attn_scores_k<<<dim3(NQ, 2), 256, 0, stream>>>(u_b, enc_mem, mask_mem, smp,
                                                   p_hlf, msc);
    // 5. online-merge + PV -> a (bf16), 4 output-quarters
    attn_pv_k<<<dim3(4, NQ), 256, 0, stream>>>(p_hlf, msc, temb_mem, smp,
                                               (unsigned*)a_b);
    // 6. CTX_h = A_h @ Wv_h + bv_h
    mfma_gemm<false, true, false, false, true><<<dim3(1, 16, NH), 256, 0, stream>>>(
        a_b, wvt, nullptr, qh_b, bv, nullptr,
        DIM, NH * DIM, DIM, DIM, DIM, DHD * DIM, DHD, DHD);
    // 7. ST0 = X + CTX @ Wo + bo
    mfma_gemm<false, true, true, true, true><<<dim3(8, 16, 1), 256, 0, stream>>>(
        qh_b, wot, st0_f, st0_b, bo, x_f, DIM, DIM, DIM, DIM, 0, 0, 0, 0);
    // 8. H1 = relu(ST0 @ f1W1 + f1b1)
    mfma_gemm<true, true, false, false, true><<<dim3(32, 16, 1), 256, 0, stream>>>(
        st0_b, f1w1t, nullptr, h1_b, f1b1, nullptr, DIM, DIM, DIM, DFF, 0, 0, 0, 0);
    // 9. T1 parts = H1 @ f1W2 (split-K=2; bias/res merged in LN1)
    mfma_gemm<false, false, false, true, false><<<dim3(8, 16, 2), 256, 0, stream>>>(
        h1_b, f1w2t, t1p_f, nullptr, nullptr, nullptr,
        1024, DFF, DFF, DIM, 1024, 1024, NQ * DIM, 0);
    // 10. DEC = X + mask * LN1(p0 + p1 + ST0 + f1b2)
    ln1_mask_add_k<<<NQ, 256, 0, stream>>>(t1p_f, st0_f, f1b2, g1, be1, smp,
                                           x_f, dec_f, dec_b);
    // 11. H2 = relu(DEC @ f2W1 + f2b1)
    mfma_gemm<true, true, false, false, true><<<dim3(32, 16, 1), 256, 0, stream>>>(
        (const unsigned short*)dec_b, f2w1t, nullptr, h2_b, f2b1, nullptr,
        DIM, DIM, DIM, DFF, 0, 0, 0, 0);
    // 12. OUT = DEC + H2 @ f2W2 + f2b2
    mfma_gemm<false, true, true, true, false><<<dim3(8, 16, 1), 256, 0, stream>>>(
        h2_b, f2w2t, out, nullptr, f2b2, dec_f, DFF, DFF, DFF, DIM, 0, 0, 0, 0);

    (void)in_sizes; (void)n_in; (void)out_size; (void)ws_size;
}